// Round 11
// baseline (212.512 us; speedup 1.0000x reference)
//
#include <hip/hip_runtime.h>
#include <hip/hip_bf16.h>
#include <hip/hip_fp16.h>

// SGC: out = (D^-1/2 A D^-1/2)^2 x W + b.
// R19: R18 + NON-TEMPORAL streaming accesses in the gathers (single change).
// Clock-scaled budget fit shows gathers = 73% of wall time and prep at its
// floor (R16/R17/R18 all 206.x). Gathers: 1 L2-line touch per edge, ~57% L2
// hit rate, MSHR-bound fills. gather2 write-allocates 25.6MB (out) and
// streams 6.4MB (edge_src) through the 4MiB L2 holding hot h1 rows ->
// pollution. nt loads for edge_src, nt stores for h1/out keep streaming
// traffic from evicting the random-row working set.
// Readout: gather2 FETCH 88 -> ~80MB and dur -2-4us(fast clk) = confirmed;
// flat = nt ineffective on gfx950 -> structural roofline.
// Carried: padded 128-B rows, R10 4-edge A/B pipelined gathers, EPB=2048
// two-pass bucket_scatter (count-cursors + memset init), 512t LDS-staged
// fine_sort, binscan folded into order, fused gather2+GEMM, xs aliases
// edge_packed. Noise band: +-10% clock swing on identical code.

#define N_NODES 100000
#define N_EDGES 1600000
#define IN_CH 48
#define OUT_CH 64
#define NBUCKETS 392             // bucket = col >> 8 (256 nodes each)
#define CAP 4608                 // slots per bucket region (mean 4082, +8.2 sigma)
#define EPB 2048                 // edges per scatter block
#define EPR 8                    // rounds of 256 edges per block (EPB/256)
#define NBLK_EDGE 782            // ceil(1.6M / 2048)
#define NBLK_BKT 391             // buckets containing real nodes
#define RSTRIDE 32               // half2 per padded row (128 B = one L2 line)

typedef __attribute__((ext_vector_type(4))) float fvec4;

// ---- scatter packed edges into fixed bucket regions (two-pass, LDS-sorted,
//      coalesced bucket-major writes; count-based cursors => memset init) ----
__global__ void bucket_scatter_kernel(const int* __restrict__ row, const int* __restrict__ col,
                                      int* __restrict__ bucketCnt, int* __restrict__ edge_packed) {
    __shared__ int lh[NBUCKETS];
    __shared__ int lofs[NBUCKETS];
    __shared__ int lbase[NBUCKETS];
    __shared__ int stage[EPB];
    __shared__ unsigned short sbkt[EPB];
    __shared__ int wsum[4];
    int tid = threadIdx.x;
    int base = blockIdx.x * EPB;
    for (int i = tid; i < NBUCKETS; i += 256) lh[i] = 0;
    __syncthreads();
    #pragma unroll
    for (int k = 0; k < EPR; k++) {
        int e = base + k * 256 + tid;
        if (e < N_EDGES) atomicAdd(&lh[col[e] >> 8], 1);
    }
    __syncthreads();
    // parallel exclusive scan of 392 counts (2 buckets/thread, 196 active)
    {
        int c0 = (tid < 196) ? lh[2 * tid] : 0;
        int c1 = (tid < 196) ? lh[2 * tid + 1] : 0;
        int s = c0 + c1;
        int incl = s;
        int lane = tid & 63, w = tid >> 6;
        #pragma unroll
        for (int o = 1; o < 64; o <<= 1) {
            int v = __shfl_up(incl, o, 64);
            if (lane >= o) incl += v;
        }
        if (lane == 63) wsum[w] = incl;
        __syncthreads();
        int wbase = 0;
        for (int k = 0; k < w; k++) wbase += wsum[k];
        int ex = wbase + incl - s;
        if (tid < 196) {
            lofs[2 * tid]     = ex;
            lofs[2 * tid + 1] = ex + c0;
        }
    }
    __syncthreads();
    for (int i = tid; i < NBUCKETS; i += 256) {
        int c = lh[i];
        if (c > 0) lbase[i] = i * CAP + atomicAdd(&bucketCnt[i], c);
        lh[i] = 0;
    }
    __syncthreads();
    // pass 2: stage records bucket-sorted in LDS (row<<8 | col&255)
    #pragma unroll
    for (int k = 0; k < EPR; k++) {
        int e = base + k * 256 + tid;
        if (e < N_EDGES) {
            int c = col[e];
            int bkt = c >> 8;
            int r = atomicAdd(&lh[bkt], 1);
            int slot = lofs[bkt] + r;
            stage[slot] = (row[e] << 8) | (c & 255);
            sbkt[slot] = (unsigned short)bkt;
        }
    }
    __syncthreads();
    // bucket-major coalesced write-out
    int total = (base + EPB <= N_EDGES) ? EPB : (N_EDGES - base);
    for (int i = tid; i < total; i += 256) {
        int bkt = sbkt[i];
        int dst = lbase[bkt] + (i - lofs[bkt]);
        if (dst < (bkt + 1) * CAP)           // overflow guard (P ~ 5e-14)
            edge_packed[dst] = stage[i];
    }
}

// ---- per-bucket fine sort -> edge_src/deg/start/dis + bin hist ----
// 512 threads; edges LDS-staged during hist (one global pass over edge_packed).
__global__ void fine_sort_kernel(const int* __restrict__ edge_packed,
                                 const int* __restrict__ bucketCnt,
                                 int* __restrict__ edge_src,
                                 int* __restrict__ deg, int* __restrict__ start,
                                 float* __restrict__ dis, int* __restrict__ binTotal) {
    __shared__ int fh[256];
    __shared__ int cur[256];
    __shared__ int bh[64];
    __shared__ int wsum2[4];
    __shared__ int stage[CAP];
    int b = blockIdx.x;
    int t = threadIdx.x;
    int s0 = b * CAP;
    int n_edges = min(bucketCnt[b], CAP);
    int nodeBase = b << 8;
    if (t < 256) fh[t] = 0;
    if (t < 64) bh[t] = 0;
    __syncthreads();
    // hist + LDS stage (single global pass)
    for (int j = t; j < n_edges; j += 512) {
        int rc = edge_packed[s0 + j];
        stage[j] = rc;
        atomicAdd(&fh[rc & 255], 1);
    }
    __syncthreads();
    // parallel exclusive scan of 256 per-node counts (shfl, waves 0-3)
    if (t < 256) {
        int c = fh[t];
        int incl = c;
        int sl = t & 63, sw = t >> 6;
        #pragma unroll
        for (int o = 1; o < 64; o <<= 1) {
            int v = __shfl_up(incl, o, 64);
            if (sl >= o) incl += v;
        }
        if (sl == 63) wsum2[sw] = incl;
        __syncthreads();
        int wbase = 0;
        for (int k = 0; k < sw; k++) wbase += wsum2[k];
        incl += wbase;
        int ex = incl - c;                    // exclusive prefix for node t
        int node = nodeBase + t;
        bool valid = (node < N_NODES);
        int d = c;
        float dv = (valid && d > 0) ? rsqrtf((float)d) : 0.0f;
        cur[t] = ex;
        if (valid) {
            deg[node] = d;
            start[node] = s0 + ex;
            dis[node] = dv;
            atomicAdd(&bh[min(d, 63)], 1);
        }
    } else {
        __syncthreads();                      // match the scan's barrier
    }
    __syncthreads();
    // permute into per-node runs (from LDS stage)
    for (int j = t; j < n_edges; j += 512) {
        int rc = stage[j];
        int p = atomicAdd(&cur[rc & 255], 1);
        edge_src[s0 + p] = rc >> 8;
    }
    __syncthreads();
    if (t < 64 && bh[t]) atomicAdd(&binTotal[t], bh[t]);
}

// ---- prescale into PADDED rows: xs[node*32 + c], 24 half2 data + 8 pad ----
__global__ void scale_kernel(const float* __restrict__ x, const float* __restrict__ dis,
                             __half2* __restrict__ xs) {
    int g = blockIdx.x * 32 + (threadIdx.x >> 3);   // node (grid covers exactly N_NODES)
    int c = (threadIdx.x & 7) * 3;
    float dd = dis[g];
    const float2* px = (const float2*)x + g * 24 + c;
    float2 v0 = px[0], v1 = px[1], v2 = px[2];
    __half2* q = xs + g * RSTRIDE + c;
    q[0] = __floats2half2_rn(v0.x * dd, v0.y * dd);
    q[1] = __floats2half2_rn(v1.x * dd, v1.y * dd);
    q[2] = __floats2half2_rn(v2.x * dd, v2.y * dd);
}

// ---- build globally degree-sorted nodeinfo (binscan folded in) ----
__global__ void order_kernel(const int* __restrict__ deg, const int* __restrict__ start,
                             const float* __restrict__ dis,
                             const int* __restrict__ binTotal, int* __restrict__ binCursor2,
                             int4* __restrict__ nodeinfo, int n) {
    __shared__ int lhist[64];
    __shared__ int lbase[64];
    int t = threadIdx.x;
    int i = blockIdx.x * 256 + t;
    if (t < 64) lhist[t] = 0;
    __syncthreads();
    int bin = 0, myrank = 0, d = 0;
    float dv = 0.0f;
    if (i < n) {
        d = deg[i];
        dv = dis[i];
        bin = min(d, 63);
        myrank = atomicAdd(&lhist[bin], 1);
    }
    __syncthreads();
    if (t < 64) {                             // wave 0 only
        int c = binTotal[t];
        int incl = c;
        #pragma unroll
        for (int o = 1; o < 64; o <<= 1) {
            int v = __shfl_up(incl, o, 64);
            if (t >= o) incl += v;
        }
        int tot = __shfl(incl, 63, 64);
        int S = tot - incl;                   // sum over bins > t = descending base
        int add = (lhist[t] > 0) ? atomicAdd(&binCursor2[t], lhist[t]) : 0;
        lbase[t] = S + add;
    }
    __syncthreads();
    if (i < n)
        nodeinfo[lbase[bin] + myrank] = make_int4(i, start[i], d, __float_as_int(dv));
}

// Per-lane row chunk: 3 consecutive half2 at row*RSTRIDE + lane*3 (12 B).
#define LOAD3(p, v0, v1, v2) { v0 = (p)[0]; v1 = (p)[1]; v2 = (p)[2]; }
#define ACC6(v0, v1, v2) { \
    float2 u0 = __half22float2(v0), u1 = __half22float2(v1), u2 = __half22float2(v2); \
    a0 += u0.x; a1 += u0.y; a2 += u1.x; a3 += u1.y; a4 += u2.x; a5 += u2.y; }
#define ACC6B(v0, v1, v2) { \
    float2 u0 = __half22float2(v0), u1 = __half22float2(v1), u2 = __half22float2(v2); \
    b0 += u0.x; b1 += u0.y; b2 += u1.x; b3 += u1.y; b4 += u2.x; b5 += u2.y; }

// ---- 2-deep software pipeline with src prefetched one stage ahead (R10).
// edge_src loads NON-TEMPORAL (streaming: no L2 promote -> preserve row cache).
#define DECLD(P) __half2 P##00,P##01,P##02,P##10,P##11,P##12,P##20,P##21,P##22,P##30,P##31,P##32
#define DECLS(S) int S##0, S##1, S##2, S##3
#define LOADSRC(S) { S##0 = __builtin_nontemporal_load(edge_src + j); \
                     S##1 = __builtin_nontemporal_load(edge_src + j + 1); \
                     S##2 = __builtin_nontemporal_load(edge_src + j + 2); \
                     S##3 = __builtin_nontemporal_load(edge_src + j + 3); j += 4; }
#define ISSUED(P, S, basep) { \
    const __half2* q0 = basep + S##0 * RSTRIDE + lane3; \
    const __half2* q1 = basep + S##1 * RSTRIDE + lane3; \
    const __half2* q2 = basep + S##2 * RSTRIDE + lane3; \
    const __half2* q3 = basep + S##3 * RSTRIDE + lane3; \
    P##00 = q0[0]; P##01 = q0[1]; P##02 = q0[2]; \
    P##10 = q1[0]; P##11 = q1[1]; P##12 = q1[2]; \
    P##20 = q2[0]; P##21 = q2[1]; P##22 = q2[2]; \
    P##30 = q3[0]; P##31 = q3[1]; P##32 = q3[2]; }
#define CONSUMED(P) { ACC6(P##00,P##01,P##02); ACC6B(P##10,P##11,P##12); \
                      ACC6(P##20,P##21,P##22); ACC6B(P##30,P##31,P##32); }

#define GATHER_PIPELINE(basep) { \
    int m = (e - s) >> 2; \
    DECLD(A); DECLD(B); \
    DECLS(sa); DECLS(sb); \
    if (m >= 2) { \
        LOADSRC(sa); LOADSRC(sb); \
        ISSUED(A, sa, basep); \
        m -= 2; \
        while (m >= 2) { \
            LOADSRC(sa); \
            ISSUED(B, sb, basep); \
            CONSUMED(A); \
            LOADSRC(sb); \
            ISSUED(A, sa, basep); \
            CONSUMED(B); \
            m -= 2; \
        } \
        if (m == 1) { \
            LOADSRC(sa); \
            ISSUED(B, sb, basep); \
            CONSUMED(A); \
            ISSUED(A, sa, basep); \
            CONSUMED(B); \
            CONSUMED(A); \
        } else { \
            ISSUED(B, sb, basep); \
            CONSUMED(A); \
            CONSUMED(B); \
        } \
    } else if (m == 1) { \
        LOADSRC(sa); \
        ISSUED(A, sa, basep); \
        CONSUMED(A); \
    } \
    for (; j < e; ++j) { \
        int srcT = __builtin_nontemporal_load(edge_src + j); \
        const __half2* p0 = basep + srcT * RSTRIDE + lane3; \
        __half2 v00, v01, v02; \
        LOAD3(p0, v00, v01, v02); \
        ACC6(v00, v01, v02); \
    } \
    a0 += b0; a1 += b1; a2 += b2; a3 += b3; a4 += b4; a5 += b5; }

// ---- gather round 1: 8 lanes/node, pipelined ----
// h1[i] = (sum_src xs[src]) * dis[i]^2   (folds round-2 source scaling)
__global__ void gather1_kernel(const __half2* __restrict__ xs,
                               const int* __restrict__ edge_src,
                               const int4* __restrict__ nodeinfo,
                               __half2* __restrict__ h1) {
    int g = blockIdx.x * 32 + (threadIdx.x >> 3);
    int lane3 = (threadIdx.x & 7) * 3;
    int4 ni = nodeinfo[g];
    int node = ni.x, s = ni.y, e = s + ni.z;
    float dv = __int_as_float(ni.w);
    float a0 = 0, a1 = 0, a2 = 0, a3 = 0, a4 = 0, a5 = 0;
    float b0 = 0, b1 = 0, b2 = 0, b3 = 0, b4 = 0, b5 = 0;
    int j = s;
    GATHER_PIPELINE(xs);
    float sc = dv * dv;
    __half2 h0 = __floats2half2_rn(a0 * sc, a1 * sc);
    __half2 h1v = __floats2half2_rn(a2 * sc, a3 * sc);
    __half2 h2 = __floats2half2_rn(a4 * sc, a5 * sc);
    // non-temporal: h1 is streaming output (re-fetched randomly next kernel
    // anyway); don't evict the hot xs rows.
    unsigned int* q = (unsigned int*)(h1 + node * RSTRIDE + lane3);
    __builtin_nontemporal_store(*(const unsigned int*)&h0, q);
    __builtin_nontemporal_store(*(const unsigned int*)&h1v, q + 1);
    __builtin_nontemporal_store(*(const unsigned int*)&h2, q + 2);
}

// ---- gather round 2 fused with GEMM ----
__global__ void gather2_gemm_kernel(const __half2* __restrict__ h1,
                                    const int* __restrict__ edge_src,
                                    const int4* __restrict__ nodeinfo,
                                    const float* __restrict__ W,
                                    const float* __restrict__ bias,
                                    float* __restrict__ out) {
    __shared__ float sW[IN_CH * OUT_CH];
    __shared__ float sb[OUT_CH];
    __shared__ float sh[32][IN_CH + 1];

    for (int i = threadIdx.x; i < IN_CH * OUT_CH; i += 256) sW[i] = W[i];
    if (threadIdx.x < OUT_CH) sb[threadIdx.x] = bias[threadIdx.x];

    int nl = threadIdx.x >> 3;
    int lane = threadIdx.x & 7;
    int lane3 = lane * 3;
    int g = blockIdx.x * 32 + nl;
    int4 ni = nodeinfo[g];
    int node = ni.x, s = ni.y, e = s + ni.z;
    float dv = __int_as_float(ni.w);

    float a0 = 0, a1 = 0, a2 = 0, a3 = 0, a4 = 0, a5 = 0;
    float b0 = 0, b1 = 0, b2 = 0, b3 = 0, b4 = 0, b5 = 0;
    int j = s;
    GATHER_PIPELINE(h1);
    int c0 = 6 * lane;
    sh[nl][c0 + 0] = a0 * dv;
    sh[nl][c0 + 1] = a1 * dv;
    sh[nl][c0 + 2] = a2 * dv;
    sh[nl][c0 + 3] = a3 * dv;
    sh[nl][c0 + 4] = a4 * dv;
    sh[nl][c0 + 5] = a5 * dv;
    __syncthreads();

    int j0 = lane * 8;
    float acc[8];
    #pragma unroll
    for (int i = 0; i < 8; i++) acc[i] = sb[j0 + i];
    for (int k = 0; k < IN_CH; k++) {
        float s0 = sh[nl][k];
        #pragma unroll
        for (int i = 0; i < 8; i++) acc[i] += s0 * sW[k * OUT_CH + j0 + i];
    }
    // non-temporal: out is write-once streaming; don't write-allocate 25.6MB
    // of L2 lines that would evict the hot h1 rows.
    fvec4 o0 = {acc[0], acc[1], acc[2], acc[3]};
    fvec4 o1 = {acc[4], acc[5], acc[6], acc[7]};
    fvec4* o = (fvec4*)(out + (size_t)node * OUT_CH + j0);
    __builtin_nontemporal_store(o0, o);
    __builtin_nontemporal_store(o1, o + 1);
}

extern "C" void kernel_launch(void* const* d_in, const int* in_sizes, int n_in,
                              void* d_out, int out_size, void* d_ws, size_t ws_size,
                              hipStream_t stream) {
    const float* x   = (const float*)d_in[0];
    const int*   ei  = (const int*)d_in[1];
    const float* W   = (const float*)d_in[2];
    const float* b   = (const float*)d_in[3];
    float* out = (float*)d_out;

    const int* row = ei;             // edge_index[0] (sources)
    const int* col = ei + N_EDGES;   // edge_index[1] (destinations)

    // ws layout (int offsets), ~35.6 MB total.
    // NOTE: xs ALIASES edge_packed's region (edge_packed dead after fine_sort;
    // xs written by scale_kernel which launches after — stream-ordered).
    int* ws_i = (int*)d_ws;
    int* bucketCnt    = ws_i;                       // [512]  (counts; base = bkt*CAP + cnt)
    int* binTotal     = ws_i + 512;                 // [64]
    int* binCursor2   = ws_i + 576;                 // [64]   (cross-block rank counters)
    int* deg          = ws_i + 1024;                // [100352]
    int* start        = ws_i + 101376;              // [100352]
    float* dis        = (float*)(ws_i + 201728);    // [100352]
    int4* nodeinfo    = (int4*)(ws_i + 302080);     // [100352] int4 (16B-aligned)
    int* edge_packed  = ws_i + 703488;              // [1806336]  (dies at fine_sort)
    __half2* xs       = (__half2*)(ws_i + 703488);  // [3200000] half2 = 12.8 MB (padded rows)
    int* edge_src     = ws_i + 3903488;             // [1806336]
    __half2* h1       = (__half2*)(ws_i + 5709824); // [3200000] half2 = 12.8 MB (padded rows)

    // zero bucketCnt + binTotal + binCursor2 in one shot
    hipMemsetAsync(d_ws, 0, 640 * sizeof(int), stream);

    bucket_scatter_kernel<<<NBLK_EDGE, 256, 0, stream>>>(row, col, bucketCnt, edge_packed);
    fine_sort_kernel<<<NBLK_BKT, 512, 0, stream>>>(edge_packed, bucketCnt,
                                                   edge_src, deg, start, dis, binTotal);
    scale_kernel<<<N_NODES / 32, 256, 0, stream>>>(x, dis, xs);
    order_kernel<<<(N_NODES + 255) / 256, 256, 0, stream>>>(deg, start, dis, binTotal,
                                                            binCursor2, nodeinfo, N_NODES);

    // 32 nodes per 256-thread block; 100000/32 = 3125 exactly
    gather1_kernel<<<N_NODES / 32, 256, 0, stream>>>(xs, edge_src, nodeinfo, h1);
    gather2_gemm_kernel<<<N_NODES / 32, 256, 0, stream>>>(h1, edge_src, nodeinfo, W, b, out);
}

// Round 12
// 205.536 us; speedup vs baseline: 1.0339x; 1.0339x over previous
//
#include <hip/hip_runtime.h>
#include <hip/hip_bf16.h>
#include <hip/hip_fp16.h>

// SGC: out = (D^-1/2 A D^-1/2)^2 x W + b.
// R20: revert R19's non-temporal experiment (REGRESSION: FETCH 88->94MB,
// gather2 +4us real — gfx950 nt bypasses L2, so nt-stored h1 lines were not
// resident for gather2's random rereads and nt edge_src loads lost free L2
// hits). Byte-identical to R18 (206.4us, best band).
// Axis ledger (all measured): pipeline depth null; slicing regress; inverted
// gather 10x disaster; 128B padding WIN (kept); global sort 16x write-amp;
// prep variants x3 all 206.x (floor); nt regress. Structure is at its
// roofline: gathers = 1 compulsory line-touch/edge @ 57% L2 hit, MSHR x
// latency bound; prep at intrinsic floor; +-10% DVFS band.
// Carried: padded 128-B rows, R10 4-edge A/B pipelined gathers, EPB=2048
// two-pass bucket_scatter (count-cursors + memset init), 512t LDS-staged
// fine_sort, binscan folded into order, fused gather2+GEMM, xs aliases
// edge_packed.

#define N_NODES 100000
#define N_EDGES 1600000
#define IN_CH 48
#define OUT_CH 64
#define NBUCKETS 392             // bucket = col >> 8 (256 nodes each)
#define CAP 4608                 // slots per bucket region (mean 4082, +8.2 sigma)
#define EPB 2048                 // edges per scatter block
#define EPR 8                    // rounds of 256 edges per block (EPB/256)
#define NBLK_EDGE 782            // ceil(1.6M / 2048)
#define NBLK_BKT 391             // buckets containing real nodes
#define RSTRIDE 32               // half2 per padded row (128 B = one L2 line)

// ---- scatter packed edges into fixed bucket regions (two-pass, LDS-sorted,
//      coalesced bucket-major writes; count-based cursors => memset init) ----
__global__ void bucket_scatter_kernel(const int* __restrict__ row, const int* __restrict__ col,
                                      int* __restrict__ bucketCnt, int* __restrict__ edge_packed) {
    __shared__ int lh[NBUCKETS];
    __shared__ int lofs[NBUCKETS];
    __shared__ int lbase[NBUCKETS];
    __shared__ int stage[EPB];
    __shared__ unsigned short sbkt[EPB];
    __shared__ int wsum[4];
    int tid = threadIdx.x;
    int base = blockIdx.x * EPB;
    for (int i = tid; i < NBUCKETS; i += 256) lh[i] = 0;
    __syncthreads();
    #pragma unroll
    for (int k = 0; k < EPR; k++) {
        int e = base + k * 256 + tid;
        if (e < N_EDGES) atomicAdd(&lh[col[e] >> 8], 1);
    }
    __syncthreads();
    // parallel exclusive scan of 392 counts (2 buckets/thread, 196 active)
    {
        int c0 = (tid < 196) ? lh[2 * tid] : 0;
        int c1 = (tid < 196) ? lh[2 * tid + 1] : 0;
        int s = c0 + c1;
        int incl = s;
        int lane = tid & 63, w = tid >> 6;
        #pragma unroll
        for (int o = 1; o < 64; o <<= 1) {
            int v = __shfl_up(incl, o, 64);
            if (lane >= o) incl += v;
        }
        if (lane == 63) wsum[w] = incl;
        __syncthreads();
        int wbase = 0;
        for (int k = 0; k < w; k++) wbase += wsum[k];
        int ex = wbase + incl - s;
        if (tid < 196) {
            lofs[2 * tid]     = ex;
            lofs[2 * tid + 1] = ex + c0;
        }
    }
    __syncthreads();
    for (int i = tid; i < NBUCKETS; i += 256) {
        int c = lh[i];
        if (c > 0) lbase[i] = i * CAP + atomicAdd(&bucketCnt[i], c);
        lh[i] = 0;
    }
    __syncthreads();
    // pass 2: stage records bucket-sorted in LDS (row<<8 | col&255)
    #pragma unroll
    for (int k = 0; k < EPR; k++) {
        int e = base + k * 256 + tid;
        if (e < N_EDGES) {
            int c = col[e];
            int bkt = c >> 8;
            int r = atomicAdd(&lh[bkt], 1);
            int slot = lofs[bkt] + r;
            stage[slot] = (row[e] << 8) | (c & 255);
            sbkt[slot] = (unsigned short)bkt;
        }
    }
    __syncthreads();
    // bucket-major coalesced write-out
    int total = (base + EPB <= N_EDGES) ? EPB : (N_EDGES - base);
    for (int i = tid; i < total; i += 256) {
        int bkt = sbkt[i];
        int dst = lbase[bkt] + (i - lofs[bkt]);
        if (dst < (bkt + 1) * CAP)           // overflow guard (P ~ 5e-14)
            edge_packed[dst] = stage[i];
    }
}

// ---- per-bucket fine sort -> edge_src/deg/start/dis + bin hist ----
// 512 threads; edges LDS-staged during hist (one global pass over edge_packed).
__global__ void fine_sort_kernel(const int* __restrict__ edge_packed,
                                 const int* __restrict__ bucketCnt,
                                 int* __restrict__ edge_src,
                                 int* __restrict__ deg, int* __restrict__ start,
                                 float* __restrict__ dis, int* __restrict__ binTotal) {
    __shared__ int fh[256];
    __shared__ int cur[256];
    __shared__ int bh[64];
    __shared__ int wsum2[4];
    __shared__ int stage[CAP];
    int b = blockIdx.x;
    int t = threadIdx.x;
    int s0 = b * CAP;
    int n_edges = min(bucketCnt[b], CAP);
    int nodeBase = b << 8;
    if (t < 256) fh[t] = 0;
    if (t < 64) bh[t] = 0;
    __syncthreads();
    // hist + LDS stage (single global pass)
    for (int j = t; j < n_edges; j += 512) {
        int rc = edge_packed[s0 + j];
        stage[j] = rc;
        atomicAdd(&fh[rc & 255], 1);
    }
    __syncthreads();
    // parallel exclusive scan of 256 per-node counts (shfl, waves 0-3)
    if (t < 256) {
        int c = fh[t];
        int incl = c;
        int sl = t & 63, sw = t >> 6;
        #pragma unroll
        for (int o = 1; o < 64; o <<= 1) {
            int v = __shfl_up(incl, o, 64);
            if (sl >= o) incl += v;
        }
        if (sl == 63) wsum2[sw] = incl;
        __syncthreads();
        int wbase = 0;
        for (int k = 0; k < sw; k++) wbase += wsum2[k];
        incl += wbase;
        int ex = incl - c;                    // exclusive prefix for node t
        int node = nodeBase + t;
        bool valid = (node < N_NODES);
        int d = c;
        float dv = (valid && d > 0) ? rsqrtf((float)d) : 0.0f;
        cur[t] = ex;
        if (valid) {
            deg[node] = d;
            start[node] = s0 + ex;
            dis[node] = dv;
            atomicAdd(&bh[min(d, 63)], 1);
        }
    } else {
        __syncthreads();                      // match the scan's barrier
    }
    __syncthreads();
    // permute into per-node runs (from LDS stage)
    for (int j = t; j < n_edges; j += 512) {
        int rc = stage[j];
        int p = atomicAdd(&cur[rc & 255], 1);
        edge_src[s0 + p] = rc >> 8;
    }
    __syncthreads();
    if (t < 64 && bh[t]) atomicAdd(&binTotal[t], bh[t]);
}

// ---- prescale into PADDED rows: xs[node*32 + c], 24 half2 data + 8 pad ----
__global__ void scale_kernel(const float* __restrict__ x, const float* __restrict__ dis,
                             __half2* __restrict__ xs) {
    int g = blockIdx.x * 32 + (threadIdx.x >> 3);   // node (grid covers exactly N_NODES)
    int c = (threadIdx.x & 7) * 3;
    float dd = dis[g];
    const float2* px = (const float2*)x + g * 24 + c;
    float2 v0 = px[0], v1 = px[1], v2 = px[2];
    __half2* q = xs + g * RSTRIDE + c;
    q[0] = __floats2half2_rn(v0.x * dd, v0.y * dd);
    q[1] = __floats2half2_rn(v1.x * dd, v1.y * dd);
    q[2] = __floats2half2_rn(v2.x * dd, v2.y * dd);
}

// ---- build globally degree-sorted nodeinfo (binscan folded in) ----
__global__ void order_kernel(const int* __restrict__ deg, const int* __restrict__ start,
                             const float* __restrict__ dis,
                             const int* __restrict__ binTotal, int* __restrict__ binCursor2,
                             int4* __restrict__ nodeinfo, int n) {
    __shared__ int lhist[64];
    __shared__ int lbase[64];
    int t = threadIdx.x;
    int i = blockIdx.x * 256 + t;
    if (t < 64) lhist[t] = 0;
    __syncthreads();
    int bin = 0, myrank = 0, d = 0;
    float dv = 0.0f;
    if (i < n) {
        d = deg[i];
        dv = dis[i];
        bin = min(d, 63);
        myrank = atomicAdd(&lhist[bin], 1);
    }
    __syncthreads();
    if (t < 64) {                             // wave 0 only
        int c = binTotal[t];
        int incl = c;
        #pragma unroll
        for (int o = 1; o < 64; o <<= 1) {
            int v = __shfl_up(incl, o, 64);
            if (t >= o) incl += v;
        }
        int tot = __shfl(incl, 63, 64);
        int S = tot - incl;                   // sum over bins > t = descending base
        int add = (lhist[t] > 0) ? atomicAdd(&binCursor2[t], lhist[t]) : 0;
        lbase[t] = S + add;
    }
    __syncthreads();
    if (i < n)
        nodeinfo[lbase[bin] + myrank] = make_int4(i, start[i], d, __float_as_int(dv));
}

// Per-lane row chunk: 3 consecutive half2 at row*RSTRIDE + lane*3 (12 B).
#define LOAD3(p, v0, v1, v2) { v0 = (p)[0]; v1 = (p)[1]; v2 = (p)[2]; }
#define ACC6(v0, v1, v2) { \
    float2 u0 = __half22float2(v0), u1 = __half22float2(v1), u2 = __half22float2(v2); \
    a0 += u0.x; a1 += u0.y; a2 += u1.x; a3 += u1.y; a4 += u2.x; a5 += u2.y; }
#define ACC6B(v0, v1, v2) { \
    float2 u0 = __half22float2(v0), u1 = __half22float2(v1), u2 = __half22float2(v2); \
    b0 += u0.x; b1 += u0.y; b2 += u1.x; b3 += u1.y; b4 += u2.x; b5 += u2.y; }

// ---- 2-deep software pipeline with src prefetched one stage ahead (R10) ----
#define DECLD(P) __half2 P##00,P##01,P##02,P##10,P##11,P##12,P##20,P##21,P##22,P##30,P##31,P##32
#define DECLS(S) int S##0, S##1, S##2, S##3
#define LOADSRC(S) { S##0 = edge_src[j]; S##1 = edge_src[j+1]; \
                     S##2 = edge_src[j+2]; S##3 = edge_src[j+3]; j += 4; }
#define ISSUED(P, S, basep) { \
    const __half2* q0 = basep + S##0 * RSTRIDE + lane3; \
    const __half2* q1 = basep + S##1 * RSTRIDE + lane3; \
    const __half2* q2 = basep + S##2 * RSTRIDE + lane3; \
    const __half2* q3 = basep + S##3 * RSTRIDE + lane3; \
    P##00 = q0[0]; P##01 = q0[1]; P##02 = q0[2]; \
    P##10 = q1[0]; P##11 = q1[1]; P##12 = q1[2]; \
    P##20 = q2[0]; P##21 = q2[1]; P##22 = q2[2]; \
    P##30 = q3[0]; P##31 = q3[1]; P##32 = q3[2]; }
#define CONSUMED(P) { ACC6(P##00,P##01,P##02); ACC6B(P##10,P##11,P##12); \
                      ACC6(P##20,P##21,P##22); ACC6B(P##30,P##31,P##32); }

#define GATHER_PIPELINE(basep) { \
    int m = (e - s) >> 2; \
    DECLD(A); DECLD(B); \
    DECLS(sa); DECLS(sb); \
    if (m >= 2) { \
        LOADSRC(sa); LOADSRC(sb); \
        ISSUED(A, sa, basep); \
        m -= 2; \
        while (m >= 2) { \
            LOADSRC(sa); \
            ISSUED(B, sb, basep); \
            CONSUMED(A); \
            LOADSRC(sb); \
            ISSUED(A, sa, basep); \
            CONSUMED(B); \
            m -= 2; \
        } \
        if (m == 1) { \
            LOADSRC(sa); \
            ISSUED(B, sb, basep); \
            CONSUMED(A); \
            ISSUED(A, sa, basep); \
            CONSUMED(B); \
            CONSUMED(A); \
        } else { \
            ISSUED(B, sb, basep); \
            CONSUMED(A); \
            CONSUMED(B); \
        } \
    } else if (m == 1) { \
        LOADSRC(sa); \
        ISSUED(A, sa, basep); \
        CONSUMED(A); \
    } \
    for (; j < e; ++j) { \
        const __half2* p0 = basep + edge_src[j] * RSTRIDE + lane3; \
        __half2 v00, v01, v02; \
        LOAD3(p0, v00, v01, v02); \
        ACC6(v00, v01, v02); \
    } \
    a0 += b0; a1 += b1; a2 += b2; a3 += b3; a4 += b4; a5 += b5; }

// ---- gather round 1: 8 lanes/node, pipelined ----
// h1[i] = (sum_src xs[src]) * dis[i]^2   (folds round-2 source scaling)
__global__ void gather1_kernel(const __half2* __restrict__ xs,
                               const int* __restrict__ edge_src,
                               const int4* __restrict__ nodeinfo,
                               __half2* __restrict__ h1) {
    int g = blockIdx.x * 32 + (threadIdx.x >> 3);
    int lane3 = (threadIdx.x & 7) * 3;
    int4 ni = nodeinfo[g];
    int node = ni.x, s = ni.y, e = s + ni.z;
    float dv = __int_as_float(ni.w);
    float a0 = 0, a1 = 0, a2 = 0, a3 = 0, a4 = 0, a5 = 0;
    float b0 = 0, b1 = 0, b2 = 0, b3 = 0, b4 = 0, b5 = 0;
    int j = s;
    GATHER_PIPELINE(xs);
    float sc = dv * dv;
    __half2* q = h1 + node * RSTRIDE + lane3;
    q[0] = __floats2half2_rn(a0 * sc, a1 * sc);
    q[1] = __floats2half2_rn(a2 * sc, a3 * sc);
    q[2] = __floats2half2_rn(a4 * sc, a5 * sc);
}

// ---- gather round 2 fused with GEMM ----
__global__ void gather2_gemm_kernel(const __half2* __restrict__ h1,
                                    const int* __restrict__ edge_src,
                                    const int4* __restrict__ nodeinfo,
                                    const float* __restrict__ W,
                                    const float* __restrict__ bias,
                                    float* __restrict__ out) {
    __shared__ float sW[IN_CH * OUT_CH];
    __shared__ float sb[OUT_CH];
    __shared__ float sh[32][IN_CH + 1];

    for (int i = threadIdx.x; i < IN_CH * OUT_CH; i += 256) sW[i] = W[i];
    if (threadIdx.x < OUT_CH) sb[threadIdx.x] = bias[threadIdx.x];

    int nl = threadIdx.x >> 3;
    int lane = threadIdx.x & 7;
    int lane3 = lane * 3;
    int g = blockIdx.x * 32 + nl;
    int4 ni = nodeinfo[g];
    int node = ni.x, s = ni.y, e = s + ni.z;
    float dv = __int_as_float(ni.w);

    float a0 = 0, a1 = 0, a2 = 0, a3 = 0, a4 = 0, a5 = 0;
    float b0 = 0, b1 = 0, b2 = 0, b3 = 0, b4 = 0, b5 = 0;
    int j = s;
    GATHER_PIPELINE(h1);
    int c0 = 6 * lane;
    sh[nl][c0 + 0] = a0 * dv;
    sh[nl][c0 + 1] = a1 * dv;
    sh[nl][c0 + 2] = a2 * dv;
    sh[nl][c0 + 3] = a3 * dv;
    sh[nl][c0 + 4] = a4 * dv;
    sh[nl][c0 + 5] = a5 * dv;
    __syncthreads();

    int j0 = lane * 8;
    float acc[8];
    #pragma unroll
    for (int i = 0; i < 8; i++) acc[i] = sb[j0 + i];
    for (int k = 0; k < IN_CH; k++) {
        float s0 = sh[nl][k];
        #pragma unroll
        for (int i = 0; i < 8; i++) acc[i] += s0 * sW[k * OUT_CH + j0 + i];
    }
    float4* o = (float4*)(out + (size_t)node * OUT_CH + j0);
    o[0] = make_float4(acc[0], acc[1], acc[2], acc[3]);
    o[1] = make_float4(acc[4], acc[5], acc[6], acc[7]);
}

extern "C" void kernel_launch(void* const* d_in, const int* in_sizes, int n_in,
                              void* d_out, int out_size, void* d_ws, size_t ws_size,
                              hipStream_t stream) {
    const float* x   = (const float*)d_in[0];
    const int*   ei  = (const int*)d_in[1];
    const float* W   = (const float*)d_in[2];
    const float* b   = (const float*)d_in[3];
    float* out = (float*)d_out;

    const int* row = ei;             // edge_index[0] (sources)
    const int* col = ei + N_EDGES;   // edge_index[1] (destinations)

    // ws layout (int offsets), ~35.6 MB total.
    // NOTE: xs ALIASES edge_packed's region (edge_packed dead after fine_sort;
    // xs written by scale_kernel which launches after — stream-ordered).
    int* ws_i = (int*)d_ws;
    int* bucketCnt    = ws_i;                       // [512]  (counts; base = bkt*CAP + cnt)
    int* binTotal     = ws_i + 512;                 // [64]
    int* binCursor2   = ws_i + 576;                 // [64]   (cross-block rank counters)
    int* deg          = ws_i + 1024;                // [100352]
    int* start        = ws_i + 101376;              // [100352]
    float* dis        = (float*)(ws_i + 201728);    // [100352]
    int4* nodeinfo    = (int4*)(ws_i + 302080);     // [100352] int4 (16B-aligned)
    int* edge_packed  = ws_i + 703488;              // [1806336]  (dies at fine_sort)
    __half2* xs       = (__half2*)(ws_i + 703488);  // [3200000] half2 = 12.8 MB (padded rows)
    int* edge_src     = ws_i + 3903488;             // [1806336]
    __half2* h1       = (__half2*)(ws_i + 5709824); // [3200000] half2 = 12.8 MB (padded rows)

    // zero bucketCnt + binTotal + binCursor2 in one shot
    hipMemsetAsync(d_ws, 0, 640 * sizeof(int), stream);

    bucket_scatter_kernel<<<NBLK_EDGE, 256, 0, stream>>>(row, col, bucketCnt, edge_packed);
    fine_sort_kernel<<<NBLK_BKT, 512, 0, stream>>>(edge_packed, bucketCnt,
                                                   edge_src, deg, start, dis, binTotal);
    scale_kernel<<<N_NODES / 32, 256, 0, stream>>>(x, dis, xs);
    order_kernel<<<(N_NODES + 255) / 256, 256, 0, stream>>>(deg, start, dis, binTotal,
                                                            binCursor2, nodeinfo, N_NODES);

    // 32 nodes per 256-thread block; 100000/32 = 3125 exactly
    gather1_kernel<<<N_NODES / 32, 256, 0, stream>>>(xs, edge_src, nodeinfo, h1);
    gather2_gemm_kernel<<<N_NODES / 32, 256, 0, stream>>>(h1, edge_src, nodeinfo, W, b, out);
}